// Round 2
// baseline (80.161 us; speedup 1.0000x reference)
//
#include <hip/hip_runtime.h>

// CenterLoss: loss = ( sum_i clamp(|x_i - c_{label_i}|^2, 1e-12, 1e12)
//                      + B*(C-1)*1e-12 ) / B
// B=16384, C=1000, D=512. The one-hot mask kills all off-label distmat
// entries; each contributes exactly 1e-12 after the post-mask clamp, folded
// in as a closed-form constant. No GEMM needed.
//
// R2 structure: 1 row per wave (max MLP, no serialized label->center
// dependency chains), per-wave partial write, wide single-block stage2.

#define B_ROWS    16384
#define C_CLASSES 1000
#define D_DIM     512
#define S1_BLOCKS 4096   // x4 waves = 16384 waves -> exactly 1 row per wave

__global__ __launch_bounds__(256) void center_loss_stage1(
    const float* __restrict__ x,
    const int*   __restrict__ labels,
    const float* __restrict__ centers,
    float*       __restrict__ partials)
{
    const int tid  = threadIdx.x;
    const int wave = tid >> 6;
    const int lane = tid & 63;
    const int row  = blockIdx.x * 4 + wave;   // always < B_ROWS

    // Issue the label load first; x loads below overlap its latency.
    const int lab = labels[row];

    const float4* __restrict__ xr = (const float4*)(x + (size_t)row * D_DIM);
    float4 xa = xr[lane];
    float4 xb = xr[lane + 64];

    const float4* __restrict__ cr = (const float4*)(centers + (size_t)lab * D_DIM);
    float4 ca = cr[lane];
    float4 cb = cr[lane + 64];

    float d0 = xa.x - ca.x, d1 = xa.y - ca.y;
    float d2 = xa.z - ca.z, d3 = xa.w - ca.w;
    float e0 = xb.x - cb.x, e1 = xb.y - cb.y;
    float e2 = xb.z - cb.z, e3 = xb.w - cb.w;

    float s = d0*d0 + d1*d1 + d2*d2 + d3*d3
            + e0*e0 + e1*e1 + e2*e2 + e3*e3;

    #pragma unroll
    for (int off = 32; off > 0; off >>= 1)
        s += __shfl_down(s, off, 64);

    if (lane == 0) {
        // reference clamps the (masked) per-entry distance
        partials[row] = fminf(fmaxf(s, 1e-12f), 1e12f);
    }
}

__global__ __launch_bounds__(1024) void center_loss_stage2(
    const float* __restrict__ partials,
    float*       __restrict__ out)
{
    const int tid  = threadIdx.x;
    const int wave = tid >> 6;         // 16 waves
    const int lane = tid & 63;

    // 16384 floats = 4096 float4; 1024 threads x 4 coalesced float4 loads
    const float4* __restrict__ p = (const float4*)partials;
    float s = 0.0f;
    #pragma unroll
    for (int i = 0; i < 4; ++i) {
        float4 v = p[tid + 1024 * i];
        s += v.x + v.y + v.z + v.w;
    }

    #pragma unroll
    for (int off = 32; off > 0; off >>= 1)
        s += __shfl_down(s, off, 64);

    __shared__ float lds[16];
    if (lane == 0) lds[wave] = s;
    __syncthreads();

    if (tid < 64) {
        float t = (lane < 16) ? lds[lane] : 0.0f;
        #pragma unroll
        for (int off = 8; off > 0; off >>= 1)
            t += __shfl_down(t, off, 64);
        if (lane == 0) {
            // masked-out zeros clamp up to 1e-12: B*(C-1) of them
            t += (float)B_ROWS * (float)(C_CLASSES - 1) * 1e-12f;
            out[0] = t / (float)B_ROWS;   // /2^14 is exact
        }
    }
}

extern "C" void kernel_launch(void* const* d_in, const int* in_sizes, int n_in,
                              void* d_out, int out_size, void* d_ws, size_t ws_size,
                              hipStream_t stream) {
    const float* x        = (const float*)d_in[0];
    const int*   labels   = (const int*)d_in[1];
    const float* centers  = (const float*)d_in[2];
    float*       out      = (float*)d_out;
    float*       partials = (float*)d_ws;   // B_ROWS floats = 64 KB

    center_loss_stage1<<<S1_BLOCKS, 256, 0, stream>>>(x, labels, centers, partials);
    center_loss_stage2<<<1, 1024, 0, stream>>>(partials, out);
}